// Round 14
// baseline (116.901 us; speedup 1.0000x reference)
//
#include <hip/hip_runtime.h>
#include <hip/hip_bf16.h>
#include <math.h>

#define B_   4
#define S_   2048
#define E_   256
#define H_   8
#define D_   32
#define FF_  1024
#define NTOK (B_*S_)   // 8192

typedef __attribute__((ext_vector_type(8))) short short8;
typedef __attribute__((ext_vector_type(4))) float f32x4;
typedef __attribute__((ext_vector_type(4))) unsigned u32x4;
typedef __hip_bfloat16 bf16;

#define QSCALE 0.09016844005556021f   // (1/16) * log2(e)

__device__ __forceinline__ unsigned short round_bf16(float a) {
    unsigned ua = __builtin_bit_cast(unsigned, a);
    return (unsigned short)((ua + 0x7fffu + ((ua >> 16) & 1u)) >> 16);
}
__device__ __forceinline__ unsigned cvtpk_bf16(float lo, float hi) {
    unsigned r;
    asm("v_cvt_pk_bf16_f32 %0, %1, %2" : "=v"(r) : "v"(lo), "v"(hi));
    return r;
}
__device__ __forceinline__ float fexp2(float x) {
    float r;
    asm("v_exp_f32 %0, %1" : "=v"(r) : "v"(x));
    return r;
}
__device__ __forceinline__ void gld16(const short* g, short* l) {
    __builtin_amdgcn_global_load_lds(
        (const __attribute__((address_space(1))) unsigned int*)g,
        (__attribute__((address_space(3))) unsigned int*)l, 16, 0, 0);
}
// GEMM LDS tile: row stride 64 shorts (128B); 16B slot index = c16 ^ (row&7)
__device__ __forceinline__ short8 lds_frag(const short* base, int r, int c16) {
    return *(const short8*)(base + r*64 + (((c16) ^ (r & 7)) << 3));
}

// ---------------- fused QKV (+V-transpose) + weight-prep + maskscan ----------------
// blocks 0..511: QKV (writes Q,K + VT directly). 512..1599: weight conv. 1600: maskscan.
// Q pre-scaled by QSCALE. K stored PERMUTED within each 64-row tile:
// token u (=s&63) -> row 32*((u>>5)&1) + 16*((u>>2)&1) + 4*((u>>3)&3) + (u&3).
__global__ __launch_bounds__(256) void qkv_prep_kernel(
    const float* __restrict__ x,
    const float* __restrict__ wq, const float* __restrict__ wk, const float* __restrict__ wv,
    bf16* __restrict__ q, bf16* __restrict__ k, unsigned short* __restrict__ vt,
    const float* __restrict__ w_out, const float* __restrict__ ff_w1,
    const float* __restrict__ ff_w2, const float* __restrict__ pr_w1,
    const float* __restrict__ pr_w2,
    unsigned short* __restrict__ woT, unsigned short* __restrict__ f1T,
    unsigned short* __restrict__ f2T, unsigned short* __restrict__ p1T,
    unsigned short* __restrict__ p2T,
    const int* __restrict__ mask, int* __restrict__ mflags)
{
    const int bid = blockIdx.x;
    if (bid >= 512) {
        const int pb = bid - 512;
        if (pb >= 1088) {   // maskscan
            const int t = threadIdx.x;
            if (t < 128) {
                const int* p = mask + (t >> 5)*S_ + (t & 31)*64;
                int any0 = 0;
                #pragma unroll
                for (int i = 0; i < 16; ++i) {
                    const int4 vv = *(const int4*)(p + i*4);
                    if (!(vv.x && vv.y && vv.z && vv.w)) any0 = 1;
                }
                mflags[t] = any0;
            }
            return;
        }
        const float* w; unsigned short* wt; int K, N, idx;
        if (pb < 64)       { w = w_out; wt = woT; K = E_;  N = E_;  idx = pb; }
        else if (pb < 320) { w = ff_w1; wt = f1T; K = E_;  N = FF_; idx = pb - 64; }
        else if (pb < 576) { w = ff_w2; wt = f2T; K = FF_; N = E_;  idx = pb - 320; }
        else if (pb < 832) { w = pr_w1; wt = p1T; K = E_;  N = FF_; idx = pb - 576; }
        else               { w = pr_w2; wt = p2T; K = FF_; N = E_;  idx = pb - 832; }
        const int nb = N/32;
        const int n0 = (idx % nb)*32, k0 = (idx / nb)*32;
        __shared__ float tile[32][33];
        const int c = threadIdx.x & 31, r0 = threadIdx.x >> 5;
        #pragma unroll
        for (int i = 0; i < 4; ++i)
            tile[r0 + 8*i][c] = w[(size_t)(k0 + r0 + 8*i)*N + n0 + c];
        __syncthreads();
        #pragma unroll
        for (int i = 0; i < 4; ++i)
            wt[(size_t)(n0 + r0 + 8*i)*K + k0 + c] = round_bf16(tile[c][r0 + 8*i]);
        return;
    }
    // ---- QKV ----
    __shared__ float wqs[D_*D_], wks[D_*D_], wvs[D_*D_];
    __shared__ float xs[16][E_];
    __shared__ unsigned short vsh[16*256];
    const int tid = threadIdx.x;
    for (int i = tid; i < D_*D_; i += 256) {
        wqs[i] = wq[i]; wks[i] = wk[i]; wvs[i] = wv[i];
    }
    const int tok0 = bid * 16;
    #pragma unroll
    for (int i = 0; i < 16; ++i)
        xs[i][tid] = x[(size_t)(tok0 + i)*E_ + tid];
    __syncthreads();
    const int h = tid >> 5, d = tid & 31;
    const int b  = tok0 >> 11;
    const int s0 = tok0 & (S_-1);
    for (int t = 0; t < 16; ++t) {
        float aq = 0.f, ak = 0.f, av = 0.f;
        #pragma unroll
        for (int i = 0; i < D_; ++i) {
            const float xv = xs[t][h*D_ + i];
            aq += xv * wqs[i*D_ + d];
            ak += xv * wks[i*D_ + d];
            av += xv * wvs[i*D_ + d];
        }
        const int s = s0 + t;
        const int u = s & 63;
        const int sp = (s & ~63) | (((u>>5)&1)*32 + ((u>>2)&1)*16 + ((u>>3)&3)*4 + (u&3));
        const size_t base = (size_t)(b*H_ + h)*S_;
        q[(base + s )*D_ + d] = __float2bfloat16(aq * QSCALE);
        k[(base + sp)*D_ + d] = __float2bfloat16(ak);
        vsh[t*256 + tid] = round_bf16(av);
    }
    __syncthreads();
    // V-transpose write: thread (h,d) -> VT[(b*H+h)*D + d][s0..s0+15]  (2x16B)
    unsigned vv[8];
    #pragma unroll
    for (int i = 0; i < 8; ++i) {
        const unsigned lo = vsh[(2*i    )*256 + tid];
        const unsigned hi = vsh[(2*i + 1)*256 + tid];
        vv[i] = lo | (hi << 16);
    }
    unsigned short* dst = vt + ((size_t)((b*H_ + h)*D_ + d))*S_ + s0;
    *(u32x4*)(dst)     = (u32x4){vv[0], vv[1], vv[2], vv[3]};
    *(u32x4*)(dst + 8) = (u32x4){vv[4], vv[5], vv[6], vv[7]};
}

// ---------------- MFMA flash attention ----------------
// Block = 8 waves (512 thr) = 4 q-groups (32 q each) x 2 key-halves (16 tiles each).
// K LDS [64 rows][32], read slot = g ^ ((c>>1)&3); V LDS [32 d][64 keys], read
// slot = s ^ (c&7); sources inverse-swizzled (both-sides rule).
// No max-tracking: P = exp2(sc) exactly. Row-sum l via MFMA ones-trick.
// Halves merged at the end via LDS (pure o/l add).
__global__ __launch_bounds__(512) void attn_mfma_kernel(
    const short* __restrict__ qg, const short* __restrict__ kg,
    const short* __restrict__ vtg, const int* __restrict__ mask,
    const int* __restrict__ mflags, unsigned short* __restrict__ attn_out)
{
    __shared__ alignas(16) short lk[2][2][2048];   // [buf][half][64x32]
    __shared__ alignas(16) short lv[2][2][2048];   // [buf][half][32x64]

    const int tid  = threadIdx.x;
    const int lane = tid & 63;
    const int wid  = tid >> 6;       // 0..7
    const int c    = lane & 15;
    const int g    = lane >> 4;
    const int half = wid >> 2;       // compute key-half
    const int qs   = wid & 3;        // q-group
    // XCD swizzle: 512 blocks, 8 XCDs
    const int p    = ((int)blockIdx.x & 7)*64 + ((int)blockIdx.x >> 3);
    const int bh   = p >> 4;
    const int qt   = p & 15;
    const int b    = bh >> 3;
    const int h    = bh & 7;
    const int q0   = qt*128 + qs*32;

    const short* qrow = qg + ((size_t)bh*S_ + q0 + c)*D_ + g*8;
    const short8 qfA = *(const short8*)(qrow);
    const short8 qfB = *(const short8*)(qrow + 16*D_);
    const short* kbase = kg  + (size_t)bh*S_*D_;
    const short* vbase = vtg + (size_t)bh*D_*S_;
    const int*   mrow  = mask + b*S_;

    const int fl = (lane < 32) ? mflags[b*32 + lane] : 0;
    const unsigned long long mbits = __ballot(fl != 0);

    // staging roles: wid 0,1 -> K half0; 2,3 -> K half1; 4,5 -> V half0; 6,7 -> V half1
    const int sthalf = (wid >> 1) & 1;
    const int subw   = wid & 1;
    const short* sbase; int soff0, soff1, sinc, dchunk;
    if (wid < 4) {
        const int R0 = subw*32 + (lane >> 2);
        const int R1 = R0 + 16;
        const int s  = lane & 3;
        soff0 = R0*D_ + ((s ^ ((R0 >> 1) & 3)) << 3);
        soff1 = R1*D_ + ((s ^ ((R1 >> 1) & 3)) << 3);
        sbase = kbase + (size_t)sthalf*16*64*D_;
        sinc  = 64*D_;
        dchunk = subw*1024;
    } else {
        const int r0 = subw*16 + (lane >> 3);
        const int r1 = r0 + 8;
        const int s  = lane & 7;
        soff0 = r0*S_ + ((s ^ (r0 & 7)) << 3);
        soff1 = r1*S_ + ((s ^ (r1 & 7)) << 3);
        sbase = vbase + sthalf*16*64;
        sinc  = 64;
        dchunk = subw*1024;
    }

    const int kaddr = c*D_ + ((g ^ ((c >> 1) & 3)) << 3);
    const int va0   = c*64 + ((g       ^ (c & 7)) << 3);
    const int va1   = c*64 + (((g + 4) ^ (c & 7)) << 3);
    const f32x4 zero = {0.f,0.f,0.f,0.f};
    const short8 ones = { (short)0x3F80, (short)0x3F80, (short)0x3F80, (short)0x3F80,
                          (short)0x3F80, (short)0x3F80, (short)0x3F80, (short)0x3F80 };
    f32x4 oA0 = zero, oA1 = zero, oB0 = zero, oB1 = zero;
    f32x4 lAacc = zero, lBacc = zero;

    {   // prologue: stage tile 0 of both halves into buf 0
        short* d0 = (wid < 4 ? &lk[0][sthalf][0] : &lv[0][sthalf][0]) + dchunk;
        gld16(sbase + soff0, d0);
        gld16(sbase + soff1, d0 + 512);
    }
    __syncthreads();

    int buf = 0;
    for (int t = 0; t < 16; ++t) {
        if (t < 15) {
            const short* sp = sbase + (size_t)(t + 1)*sinc;
            short* d0 = (wid < 4 ? &lk[buf ^ 1][sthalf][0] : &lv[buf ^ 1][sthalf][0]) + dchunk;
            gld16(sp + soff0, d0);
            gld16(sp + soff1, d0 + 512);
        }
        const short* LK = &lk[buf][half][0];
        const short* LV = &lv[buf][half][0];
        const short8 kf0 = *(const short8*)(LK + kaddr);
        const short8 kf1 = *(const short8*)(LK + kaddr + 512);
        const short8 kf2 = *(const short8*)(LK + kaddr + 1024);
        const short8 kf3 = *(const short8*)(LK + kaddr + 1536);
        __builtin_amdgcn_s_setprio(1);
        f32x4 sA0 = __builtin_amdgcn_mfma_f32_16x16x32_bf16(kf0, qfA, zero, 0, 0, 0);
        f32x4 sA1 = __builtin_amdgcn_mfma_f32_16x16x32_bf16(kf1, qfA, zero, 0, 0, 0);
        f32x4 sA2 = __builtin_amdgcn_mfma_f32_16x16x32_bf16(kf2, qfA, zero, 0, 0, 0);
        f32x4 sA3 = __builtin_amdgcn_mfma_f32_16x16x32_bf16(kf3, qfA, zero, 0, 0, 0);
        f32x4 sB0 = __builtin_amdgcn_mfma_f32_16x16x32_bf16(kf0, qfB, zero, 0, 0, 0);
        f32x4 sB1 = __builtin_amdgcn_mfma_f32_16x16x32_bf16(kf1, qfB, zero, 0, 0, 0);
        f32x4 sB2 = __builtin_amdgcn_mfma_f32_16x16x32_bf16(kf2, qfB, zero, 0, 0, 0);
        f32x4 sB3 = __builtin_amdgcn_mfma_f32_16x16x32_bf16(kf3, qfB, zero, 0, 0, 0);
        __builtin_amdgcn_s_setprio(0);
        // mask; key = 64*tt + 32*(f>>1) + 8g + 4*(f&1) + r
        const int tt = half*16 + t;
        if ((mbits >> tt) & 1ull) {
            const int kb = tt*64 + 8*g;
            #pragma unroll
            for (int r = 0; r < 4; ++r) {
                if (mrow[kb      + r] == 0) { sA0[r] = -1e20f; sB0[r] = -1e20f; }
                if (mrow[kb + 4  + r] == 0) { sA1[r] = -1e20f; sB1[r] = -1e20f; }
                if (mrow[kb + 32 + r] == 0) { sA2[r] = -1e20f; sB2[r] = -1e20f; }
                if (mrow[kb + 36 + r] == 0) { sA3[r] = -1e20f; sB3[r] = -1e20f; }
            }
        }
        f32x4 pA0, pA1, pA2, pA3, pB0, pB1, pB2, pB3;
        #pragma unroll
        for (int r = 0; r < 4; ++r) {
            pA0[r] = fexp2(sA0[r]); pA1[r] = fexp2(sA1[r]);
            pA2[r] = fexp2(sA2[r]); pA3[r] = fexp2(sA3[r]);
            pB0[r] = fexp2(sB0[r]); pB1[r] = fexp2(sB1[r]);
            pB2[r] = fexp2(sB2[r]); pB3[r] = fexp2(sB3[r]);
        }
        const short8 pafA0 = __builtin_bit_cast(short8,
            (u32x4){ cvtpk_bf16(pA0[0],pA0[1]), cvtpk_bf16(pA0[2],pA0[3]),
                     cvtpk_bf16(pA1[0],pA1[1]), cvtpk_bf16(pA1[2],pA1[3]) });
        const short8 pafA1 = __builtin_bit_cast(short8,
            (u32x4){ cvtpk_bf16(pA2[0],pA2[1]), cvtpk_bf16(pA2[2],pA2[3]),
                     cvtpk_bf16(pA3[0],pA3[1]), cvtpk_bf16(pA3[2],pA3[3]) });
        const short8 pafB0 = __builtin_bit_cast(short8,
            (u32x4){ cvtpk_bf16(pB0[0],pB0[1]), cvtpk_bf16(pB0[2],pB0[3]),
                     cvtpk_bf16(pB1[0],pB1[1]), cvtpk_bf16(pB1[2],pB1[3]) });
        const short8 pafB1 = __builtin_bit_cast(short8,
            (u32x4){ cvtpk_bf16(pB2[0],pB2[1]), cvtpk_bf16(pB2[2],pB2[3]),
                     cvtpk_bf16(pB3[0],pB3[1]), cvtpk_bf16(pB3[2],pB3[3]) });
        const short8 vf0 = *(const short8*)(LV + va0);
        const short8 vf1 = *(const short8*)(LV + va1);
        const short8 vf2 = *(const short8*)(LV + va0 + 1024);
        const short8 vf3 = *(const short8*)(LV + va1 + 1024);
        __builtin_amdgcn_s_setprio(1);
        oA0 = __builtin_amdgcn_mfma_f32_16x16x32_bf16(vf0, pafA0, oA0, 0, 0, 0);
        oA0 = __builtin_amdgcn_mfma_f32_16x16x32_bf16(vf1, pafA1, oA0, 0, 0, 0);
        oA1 = __builtin_amdgcn_mfma_f32_16x16x32_bf16(vf2, pafA0, oA1, 0, 0, 0);
        oA1 = __builtin_amdgcn_mfma_f32_16x16x32_bf16(vf3, pafA1, oA1, 0, 0, 0);
        oB0 = __builtin_amdgcn_mfma_f32_16x16x32_bf16(vf0, pafB0, oB0, 0, 0, 0);
        oB0 = __builtin_amdgcn_mfma_f32_16x16x32_bf16(vf1, pafB1, oB0, 0, 0, 0);
        oB1 = __builtin_amdgcn_mfma_f32_16x16x32_bf16(vf2, pafB0, oB1, 0, 0, 0);
        oB1 = __builtin_amdgcn_mfma_f32_16x16x32_bf16(vf3, pafB1, oB1, 0, 0, 0);
        lAacc = __builtin_amdgcn_mfma_f32_16x16x32_bf16(ones, pafA0, lAacc, 0, 0, 0);
        lAacc = __builtin_amdgcn_mfma_f32_16x16x32_bf16(ones, pafA1, lAacc, 0, 0, 0);
        lBacc = __builtin_amdgcn_mfma_f32_16x16x32_bf16(ones, pafB0, lBacc, 0, 0, 0);
        lBacc = __builtin_amdgcn_mfma_f32_16x16x32_bf16(ones, pafB1, lBacc, 0, 0, 0);
        __builtin_amdgcn_s_setprio(0);
        __syncthreads();
        buf ^= 1;
    }
    // ---- merge the two key halves (pure o/l add; reuse staging LDS) ----
    float* oM = (float*)&lk[0][0][0];   // [4 qs][64 lane][16] f32 = 16KB
    float* lM = (float*)&lv[0][0][0];   // [4 qs][64 lane][2]  f32 = 2KB
    if (half == 1) {
        float* o = oM + (qs*64 + lane)*16;
        #pragma unroll
        for (int r = 0; r < 4; ++r) {
            o[r]      = oA0[r];
            o[4 + r]  = oA1[r];
            o[8 + r]  = oB0[r];
            o[12 + r] = oB1[r];
        }
        lM[(qs*64 + lane)*2 + 0] = lAacc[0];
        lM[(qs*64 + lane)*2 + 1] = lBacc[0];
    }
    __syncthreads();
    if (half == 0) {
        const float* o = oM + (qs*64 + lane)*16;
        const float lA = lAacc[0] + lM[(qs*64 + lane)*2 + 0];
        const float lB = lBacc[0] + lM[(qs*64 + lane)*2 + 1];
        const float invA = 1.0f / lA, invB = 1.0f / lB;
        unsigned short* orowA = attn_out + ((size_t)b*S_ + q0 + c)*E_ + h*D_ + g*4;
        unsigned short* orowB = orowA + (size_t)16*E_;
        uint2 a0, a1, b0, b1;
        a0.x = cvtpk_bf16((oA0[0]+o[0])*invA,  (oA0[1]+o[1])*invA);
        a0.y = cvtpk_bf16((oA0[2]+o[2])*invA,  (oA0[3]+o[3])*invA);
        a1.x = cvtpk_bf16((oA1[0]+o[4])*invA,  (oA1[1]+o[5])*invA);
        a1.y = cvtpk_bf16((oA1[2]+o[6])*invA,  (oA1[3]+o[7])*invA);
        b0.x = cvtpk_bf16((oB0[0]+o[8])*invB,  (oB0[1]+o[9])*invB);
        b0.y = cvtpk_bf16((oB0[2]+o[10])*invB, (oB0[3]+o[11])*invB);
        b1.x = cvtpk_bf16((oB1[0]+o[12])*invB, (oB1[1]+o[13])*invB);
        b1.y = cvtpk_bf16((oB1[2]+o[14])*invB, (oB1[3]+o[15])*invB);
        *(uint2*)(orowA)      = a0;
        *(uint2*)(orowA + 16) = a1;
        *(uint2*)(orowB)      = b0;
        *(uint2*)(orowB + 16) = b1;
    }
}

// ---------------- fused GEMM + series decomposition ----------------
// C = A[M,K] @ WT[256,K]^T + bias + R  (full E=256 row per block, BM=32),
// then res = C - movavg25(C) over the E axis; writes o32 (fp32) and/or ob (bf16).
// SINGLE-buffered staging (36KB LDS -> 4 blocks/CU = 16 waves/CU).
template<int WF32, int WBF16>
__global__ __launch_bounds__(256) void mgemm_dec_kernel(
    const short* __restrict__ A, const short* __restrict__ WT,
    const float* __restrict__ bias, const float* __restrict__ R,
    float* __restrict__ o32, unsigned short* __restrict__ ob,
    int M, int K)
{
    __shared__ alignas(16) short stage[18432];   // As 2048 sh + Bs 16384 sh = 36KB
    float* dec = (float*)&stage[0];              // [32][261] fp32 = 33408 B (fits)
    const int t = threadIdx.x, w = t >> 6, lane = t & 63;
    const int col = lane & 15, grp = lane >> 4;
    const int wm = w >> 1, wn = w & 1;
    const int nwg = gridDim.x;
    const int bm = ((int)blockIdx.x & 7)*(nwg >> 3) + ((int)blockIdx.x >> 3);
    const int arow = t >> 3, ac = t & 7;

    f32x4 acc[8];
    #pragma unroll
    for (int j = 0; j < 8; ++j) acc[j] = (f32x4){0.f,0.f,0.f,0.f};

    for (int kb = 0; kb < K; kb += 64) {
        {
            const int row = arow;
            gld16(A + (size_t)(bm*32 + row)*K + kb + ((ac ^ (row & 7)) << 3),
                  &stage[0] + w*512);
            #pragma unroll
            for (int b2 = 0; b2 < 8; ++b2) {
                const int rowb = b2*32 + arow;
                gld16(WT + (size_t)rowb*K + kb + ((ac ^ (rowb & 7)) << 3),
                      &stage[2048] + b2*2048 + w*512);
            }
        }
        __syncthreads();
        const short* As_ = &stage[0];
        const short* Bs_ = &stage[2048];
        #pragma unroll
        for (int s = 0; s < 2; ++s) {
            const short8 af = lds_frag(As_, wm*16 + col, s*4 + grp);
            #pragma unroll
            for (int fc = 0; fc < 8; ++fc) {
                const short8 bf_ = lds_frag(Bs_, wn*128 + fc*16 + col, s*4 + grp);
                acc[fc] = __builtin_amdgcn_mfma_f32_16x16x32_bf16(af, bf_, acc[fc], 0, 0, 0);
            }
        }
        __syncthreads();
    }

    // epilogue: bias + residual -> LDS dec[32][261]
    #pragma unroll
    for (int fc = 0; fc < 8; ++fc) {
        const int n = wn*128 + fc*16 + col;
        const float bs = bias[n];
        #pragma unroll
        for (int reg = 0; reg < 4; ++reg) {
            const int m = wm*16 + grp*4 + reg;
            float v = acc[fc][reg] + bs;
            v += R[(size_t)(bm*32 + m)*E_ + n];
            dec[m*261 + n] = v;
        }
    }
    __syncthreads();
    const int row = t & 31, ch = t >> 5;
    const int c0 = ch * 32;
    const float* dr = dec + row*261;
    float sum = 0.f;
    #pragma unroll
    for (int j = -12; j <= 12; ++j) {
        int jj = c0 + j;
        jj = jj < 0 ? 0 : (jj > 255 ? 255 : jj);
        sum += dr[jj];
    }
    float res[32];
    #pragma unroll
    for (int i = 0; i < 32; ++i) {
        const int cc = c0 + i;
        res[i] = dr[cc] - sum * (1.0f/25.0f);
        const int hi = cc + 13 > 255 ? 255 : cc + 13;
        const int lo = cc - 12 < 0 ? 0 : cc - 12;
        sum += dr[hi] - dr[lo];
    }
    const size_t gro = (size_t)(bm*32 + row)*E_ + c0;
    if (WF32) {
        #pragma unroll
        for (int i = 0; i < 8; ++i)
            *(f32x4*)(o32 + gro + i*4) = (f32x4){res[4*i], res[4*i+1], res[4*i+2], res[4*i+3]};
    }
    if (WBF16) {
        #pragma unroll
        for (int i = 0; i < 4; ++i) {
            u32x4 pk;
            #pragma unroll
            for (int j = 0; j < 4; ++j)
                pk[j] = cvtpk_bf16(res[8*i + 2*j], res[8*i + 2*j + 1]);
            *(u32x4*)(ob + gro + i*8) = pk;
        }
    }
}

// ---------------- bf16 MFMA GEMM: C[M,N] = op(A[M,K] @ WT[N,K]^T + bias) ----------------
// BK=64, 4 waves. DB=1: double-buffered (64^2 only). XCD-chunk swizzle.
template<int BM, int BN, int DB, int RELU, int RESID, int WF32, int WBF16>
__global__ __launch_bounds__(256) void mgemm_kernel(
    const short* __restrict__ A, const short* __restrict__ WT,
    const float* __restrict__ bias, const float* __restrict__ R,
    float* __restrict__ C32, unsigned short* __restrict__ Cb,
    int M, int N, int K)
{
    constexpr int FR = BM / 32;
    constexpr int FC = BN / 32;
    constexpr int NB = DB ? 2 : 1;
    __shared__ alignas(16) short As[NB][BM*64];
    __shared__ alignas(16) short Bs[NB][BN*64];
    const int t = threadIdx.x, w = t >> 6, lane = t & 63;
    const int col = lane & 15, grp = lane >> 4;
    const int wm = w >> 1, wn = w & 1;
    const int gx = N / BN;
    const int nwg = gridDim.x;
    const int lin = ((int)blockIdx.x & 7)*(nwg >> 3) + ((int)blockIdx.x >> 3);
    const int bm = lin / gx, bn = lin % gx;
    const int arow = t >> 3, ac = t & 7;

    f32x4 acc[FR][FC];
    #pragma unroll
    for (int i = 0; i < FR; ++i)
        #pragma unroll
        for (int j = 0; j < FC; ++j) acc[i][j] = (f32x4){0.f,0.f,0.f,0.f};

    if (DB) {
        #pragma unroll
        for (int b2 = 0; b2 < BM/32; ++b2) {
            const int row = b2*32 + arow;
            gld16(A + (size_t)(bm*BM + row)*K + ((ac ^ (row & 7)) << 3),
                  &As[0][0] + b2*2048 + w*512);
        }
        #pragma unroll
        for (int b2 = 0; b2 < BN/32; ++b2) {
            const int row = b2*32 + arow;
            gld16(WT + (size_t)(bn*BN + row)*K + ((ac ^ (row & 7)) << 3),
                  &Bs[0][0] + b2*2048 + w*512);
        }
        __syncthreads();
        int buf = 0;
        for (int kb = 0; kb < K; kb += 64) {
            if (kb + 64 < K) {
                #pragma unroll
                for (int b2 = 0; b2 < BM/32; ++b2) {
                    const int row = b2*32 + arow;
                    gld16(A + (size_t)(bm*BM + row)*K + kb + 64 + ((ac ^ (row & 7)) << 3),
                          &As[buf ^ 1][0] + b2*2048 + w*512);
                }
                #pragma unroll
                for (int b2 = 0; b2 < BN/32; ++b2) {
                    const int row = b2*32 + arow;
                    gld16(WT + (size_t)(bn*BN + row)*K + kb + 64 + ((ac ^ (row & 7)) << 3),
                          &Bs[buf ^ 1][0] + b2*2048 + w*512);
                }
            }
            #pragma unroll
            for (int s = 0; s < 2; ++s) {
                short8 af[FR], bf_[FC];
                #pragma unroll
                for (int fr = 0; fr < FR; ++fr)
                    af[fr] = lds_frag(&As[buf][0], wm*(BM/2) + fr*16 + col, s*4 + grp);
                #pragma unroll
                for (int fc = 0; fc < FC; ++fc)
                    bf_[fc] = lds_frag(&Bs[buf][0], wn*(BN/2) + fc*16 + col, s*4 + grp);
                #pragma unroll
                for (int fr = 0; fr < FR; ++fr)
                    #pragma unroll
                    for (int fc = 0; fc < FC; ++fc)
                        acc[fr][fc] = __builtin_amdgcn_mfma_f32_16x16x32_bf16(af[fr], bf_[fc], acc[fr][fc], 0, 0, 0);
            }
            __syncthreads();
            buf ^= 1;
        }
    } else {
        for (int kb = 0; kb < K; kb += 64) {
            #pragma unroll
            for (int b2 = 0; b2 < BM/32; ++b2) {
                const int row = b2*32 + arow;
                gld16(A + (size_t)(bm*BM + row)*K + kb + ((ac ^ (row & 7)) << 3),
                      &As[0][0] + b2*2048 + w*512);
            }
            #pragma unroll
            for (int b2 = 0; b2 < BN/32; ++b2) {
                const int row = b2*32 + arow;
                gld16(WT + (size_t)(bn*BN + row)*K + kb + ((ac ^ (row & 7)) << 3),
                      &Bs[0][0] + b2*2048 + w*512);
            }
            __syncthreads();
            #pragma unroll
            for (int s = 0; s < 2; ++s) {
                short8 af[FR], bf_[FC];
                #pragma unroll
                for (int fr = 0; fr < FR; ++fr)
                    af[fr] = lds_frag(&As[0][0], wm*(BM/2) + fr*16 + col, s*4 + grp);
                #pragma unroll
                for (int fc = 0; fc < FC; ++fc)
                    bf_[fc] = lds_frag(&Bs[0][0], wn*(BN/2) + fc*16 + col, s*4 + grp);
                #pragma unroll
                for (int fr = 0; fr < FR; ++fr)
                    #pragma unroll
                    for (int fc = 0; fc < FC; ++fc)
                        acc[fr][fc] = __builtin_amdgcn_mfma_f32_16x16x32_bf16(af[fr], bf_[fc], acc[fr][fc], 0, 0, 0);
            }
            __syncthreads();
        }
    }

    #pragma unroll
    for (int fc = 0; fc < FC; ++fc) {
        const int n = bn*BN + wn*(BN/2) + fc*16 + col;
        const float bs = bias[n];
        #pragma unroll
        for (int fr = 0; fr < FR; ++fr) {
            #pragma unroll
            for (int reg = 0; reg < 4; ++reg) {
                const int m = bm*BM + wm*(BM/2) + fr*16 + grp*4 + reg;
                float v = acc[fr][fc][reg] + bs;
                if (RELU) v = fmaxf(v, 0.f);
                if (RESID) v += R[(size_t)m*N + n];
                if (WF32) C32[(size_t)m*N + n] = v;
                if (WBF16) Cb[(size_t)m*N + n] = round_bf16(v);
            }
        }
    }
}

extern "C" void kernel_launch(void* const* d_in, const int* in_sizes, int n_in,
                              void* d_out, int out_size, void* d_ws, size_t ws_size,
                              hipStream_t stream) {
    const float* x     = (const float*)d_in[0];
    const int*   mask  = (const int*)  d_in[1];
    const float* wq    = (const float*)d_in[2];
    const float* wk    = (const float*)d_in[3];
    const float* wv    = (const float*)d_in[4];
    const float* w_out = (const float*)d_in[5];
    const float* b_out = (const float*)d_in[6];
    const float* ff_w1 = (const float*)d_in[7];
    const float* ff_b1 = (const float*)d_in[8];
    const float* ff_w2 = (const float*)d_in[9];
    const float* ff_b2 = (const float*)d_in[10];
    const float* pr_w1 = (const float*)d_in[11];
    const float* pr_b1 = (const float*)d_in[12];
    const float* pr_w2 = (const float*)d_in[13];
    const float* pr_b2 = (const float*)d_in[14];
    float* out = (float*)d_out;

    char* ws = (char*)d_ws;
    const size_t MB = 1024ull*1024ull;
    const size_t KB = 1024ull;
    bf16*  qb    = (bf16*)(ws + 0*MB);                       // 4MB
    bf16*  kbf   = (bf16*)(ws + 4*MB);                       // 4MB
    bf16*  vtb   = (bf16*)(ws + 12*MB);                      // 4MB
    unsigned short* attnb = (unsigned short*)(ws + 16*MB);   // 4MB
    float* y32   = (float*)(ws + 28*MB);                     // 8MB
    unsigned short* yb  = (unsigned short*)(ws + 36*MB);     // 4MB
    unsigned short* h1  = (unsigned short*)(ws + 0*MB);      // 16MB (qkv dead)
    unsigned short* s2b = (unsigned short*)(ws + 16*MB);     // 4MB (attnb dead)
    unsigned short* h2  = (unsigned short*)(ws + 0*MB);      // 16MB (h1 dead)
    unsigned short* woT = (unsigned short*)(ws + 40*MB);                // 128KB
    unsigned short* f1T = (unsigned short*)(ws + 40*MB + 128*KB);       // 512KB
    unsigned short* f2T = (unsigned short*)(ws + 40*MB + 640*KB);       // 512KB
    unsigned short* p1T = (unsigned short*)(ws + 40*MB + 1152*KB);      // 512KB
    unsigned short* p2T = (unsigned short*)(ws + 40*MB + 1664*KB);      // 512KB
    int*            mfl = (int*)           (ws + 40*MB + 2176*KB);      // 512B

    // 1. fused QKV (+V-transpose) + weight prep + maskscan
    qkv_prep_kernel<<<1601, 256, 0, stream>>>(x, wq, wk, wv, qb, kbf,
                                              (unsigned short*)vtb,
                                              w_out, ff_w1, ff_w2, pr_w1, pr_w2,
                                              woT, f1T, f2T, p1T, p2T, mask, mfl);
    // 2. MFMA flash attention (8 waves: 4 q-groups x 2 key-halves) -> bf16
    attn_mfma_kernel<<<B_*H_*S_/128, 512, 0, stream>>>(
        (const short*)qb, (const short*)kbf, (const short*)vtb, mask, mfl, attnb);
    // 3. fused: x1 = x + attn@w_out + b_out ; y = decomp(x1)  -> y32 + yb
    mgemm_dec_kernel<1,1><<<NTOK/32, 256, 0, stream>>>(
        (const short*)attnb, (const short*)woT, b_out, x, y32, yb, NTOK, E_);
    // 4. FFN: h1 = relu(y @ ff_w1 + b1)   (128x128, single-buffered — R12 config)
    mgemm_kernel<128,128,0,1,0,0,1><<<(NTOK/128)*(FF_/128), 256, 0, stream>>>(
        (const short*)yb, (const short*)f1T, ff_b1, nullptr, nullptr, h1, NTOK, FF_, E_);
    // 5. fused: s = y + h1@ff_w2 + b2 ; s2 = decomp(s)  -> s2b
    mgemm_dec_kernel<0,1><<<NTOK/32, 256, 0, stream>>>(
        (const short*)h1, (const short*)f2T, ff_b2, y32, nullptr, s2b, NTOK, FF_);
    // 6. projection FFN  (128x128, single-buffered — R12 config)
    mgemm_kernel<128,128,0,1,0,0,1><<<(NTOK/128)*(FF_/128), 256, 0, stream>>>(
        (const short*)s2b, (const short*)p1T, pr_b1, nullptr, nullptr, h2, NTOK, FF_, E_);
    mgemm_kernel<64,64,1,0,0,1,0><<<(NTOK/64)*(E_/64), 256, 0, stream>>>(
        (const short*)h2, (const short*)p2T, pr_b2, nullptr, out, nullptr, NTOK, E_, FF_);
}

// Round 15
// 109.301 us; speedup vs baseline: 1.0695x; 1.0695x over previous
//
#include <hip/hip_runtime.h>
#include <hip/hip_bf16.h>
#include <math.h>

#define B_   4
#define S_   2048
#define E_   256
#define H_   8
#define D_   32
#define FF_  1024
#define NTOK (B_*S_)   // 8192

typedef __attribute__((ext_vector_type(8))) short short8;
typedef __attribute__((ext_vector_type(4))) float f32x4;
typedef __attribute__((ext_vector_type(4))) unsigned u32x4;
typedef __hip_bfloat16 bf16;

#define QSCALE 0.09016844005556021f   // (1/16) * log2(e)

__device__ __forceinline__ unsigned short round_bf16(float a) {
    unsigned ua = __builtin_bit_cast(unsigned, a);
    return (unsigned short)((ua + 0x7fffu + ((ua >> 16) & 1u)) >> 16);
}
__device__ __forceinline__ float bf16_to_f32(unsigned short u) {
    return __builtin_bit_cast(float, (unsigned)u << 16);
}
__device__ __forceinline__ unsigned cvtpk_bf16(float lo, float hi) {
    unsigned r;
    asm("v_cvt_pk_bf16_f32 %0, %1, %2" : "=v"(r) : "v"(lo), "v"(hi));
    return r;
}
__device__ __forceinline__ float fexp2(float x) {
    float r;
    asm("v_exp_f32 %0, %1" : "=v"(r) : "v"(x));
    return r;
}
__device__ __forceinline__ void gld16(const short* g, short* l) {
    __builtin_amdgcn_global_load_lds(
        (const __attribute__((address_space(1))) unsigned int*)g,
        (__attribute__((address_space(3))) unsigned int*)l, 16, 0, 0);
}
// GEMM LDS tile: row stride 64 shorts (128B); 16B slot index = c16 ^ (row&7)
__device__ __forceinline__ short8 lds_frag(const short* base, int r, int c16) {
    return *(const short8*)(base + r*64 + (((c16) ^ (r & 7)) << 3));
}

// ---------------- fused QKV (+V-transpose) + weight-prep + maskscan ----------------
// blocks 0..511: QKV (writes Q,K + VT directly). 512..1599: weight conv. 1600: maskscan.
// Q pre-scaled by QSCALE. K stored PERMUTED within each 64-row tile:
// token u (=s&63) -> row 32*((u>>5)&1) + 16*((u>>2)&1) + 4*((u>>3)&3) + (u&3).
__global__ __launch_bounds__(256) void qkv_prep_kernel(
    const float* __restrict__ x,
    const float* __restrict__ wq, const float* __restrict__ wk, const float* __restrict__ wv,
    bf16* __restrict__ q, bf16* __restrict__ k, unsigned short* __restrict__ vt,
    const float* __restrict__ w_out, const float* __restrict__ ff_w1,
    const float* __restrict__ ff_w2, const float* __restrict__ pr_w1,
    const float* __restrict__ pr_w2,
    unsigned short* __restrict__ woT, unsigned short* __restrict__ f1T,
    unsigned short* __restrict__ f2T, unsigned short* __restrict__ p1T,
    unsigned short* __restrict__ p2T,
    const int* __restrict__ mask, int* __restrict__ mflags)
{
    const int bid = blockIdx.x;
    if (bid >= 512) {
        const int pb = bid - 512;
        if (pb >= 1088) {   // maskscan
            const int t = threadIdx.x;
            if (t < 128) {
                const int* p = mask + (t >> 5)*S_ + (t & 31)*64;
                int any0 = 0;
                #pragma unroll
                for (int i = 0; i < 16; ++i) {
                    const int4 vv = *(const int4*)(p + i*4);
                    if (!(vv.x && vv.y && vv.z && vv.w)) any0 = 1;
                }
                mflags[t] = any0;
            }
            return;
        }
        const float* w; unsigned short* wt; int K, N, idx;
        if (pb < 64)       { w = w_out; wt = woT; K = E_;  N = E_;  idx = pb; }
        else if (pb < 320) { w = ff_w1; wt = f1T; K = E_;  N = FF_; idx = pb - 64; }
        else if (pb < 576) { w = ff_w2; wt = f2T; K = FF_; N = E_;  idx = pb - 320; }
        else if (pb < 832) { w = pr_w1; wt = p1T; K = E_;  N = FF_; idx = pb - 576; }
        else               { w = pr_w2; wt = p2T; K = FF_; N = E_;  idx = pb - 832; }
        const int nb = N/32;
        const int n0 = (idx % nb)*32, k0 = (idx / nb)*32;
        __shared__ float tile[32][33];
        const int c = threadIdx.x & 31, r0 = threadIdx.x >> 5;
        #pragma unroll
        for (int i = 0; i < 4; ++i)
            tile[r0 + 8*i][c] = w[(size_t)(k0 + r0 + 8*i)*N + n0 + c];
        __syncthreads();
        #pragma unroll
        for (int i = 0; i < 4; ++i)
            wt[(size_t)(n0 + r0 + 8*i)*K + k0 + c] = round_bf16(tile[c][r0 + 8*i]);
        return;
    }
    // ---- QKV ----
    __shared__ float wqs[D_*D_], wks[D_*D_], wvs[D_*D_];
    __shared__ float xs[16][E_];
    __shared__ unsigned short vsh[16*256];
    const int tid = threadIdx.x;
    for (int i = tid; i < D_*D_; i += 256) {
        wqs[i] = wq[i]; wks[i] = wk[i]; wvs[i] = wv[i];
    }
    const int tok0 = bid * 16;
    #pragma unroll
    for (int i = 0; i < 16; ++i)
        xs[i][tid] = x[(size_t)(tok0 + i)*E_ + tid];
    __syncthreads();
    const int h = tid >> 5, d = tid & 31;
    const int b  = tok0 >> 11;
    const int s0 = tok0 & (S_-1);
    for (int t = 0; t < 16; ++t) {
        float aq = 0.f, ak = 0.f, av = 0.f;
        #pragma unroll
        for (int i = 0; i < D_; ++i) {
            const float xv = xs[t][h*D_ + i];
            aq += xv * wqs[i*D_ + d];
            ak += xv * wks[i*D_ + d];
            av += xv * wvs[i*D_ + d];
        }
        const int s = s0 + t;
        const int u = s & 63;
        const int sp = (s & ~63) | (((u>>5)&1)*32 + ((u>>2)&1)*16 + ((u>>3)&3)*4 + (u&3));
        const size_t base = (size_t)(b*H_ + h)*S_;
        q[(base + s )*D_ + d] = __float2bfloat16(aq * QSCALE);
        k[(base + sp)*D_ + d] = __float2bfloat16(ak);
        vsh[t*256 + tid] = round_bf16(av);
    }
    __syncthreads();
    // V-transpose write: thread (h,d) -> VT[(b*H+h)*D + d][s0..s0+15]  (2x16B)
    unsigned vv[8];
    #pragma unroll
    for (int i = 0; i < 8; ++i) {
        const unsigned lo = vsh[(2*i    )*256 + tid];
        const unsigned hi = vsh[(2*i + 1)*256 + tid];
        vv[i] = lo | (hi << 16);
    }
    unsigned short* dst = vt + ((size_t)((b*H_ + h)*D_ + d))*S_ + s0;
    *(u32x4*)(dst)     = (u32x4){vv[0], vv[1], vv[2], vv[3]};
    *(u32x4*)(dst + 8) = (u32x4){vv[4], vv[5], vv[6], vv[7]};
}

// ---------------- MFMA flash attention ----------------
// Block = 8 waves (512 thr) = 4 q-groups (32 q each) x 2 key-halves (16 tiles each).
// K LDS [64 rows][32], read slot = g ^ ((c>>1)&3); V LDS [32 d][64 keys], read
// slot = s ^ (c&7); sources inverse-swizzled (both-sides rule).
// No max-tracking: P = exp2(sc) exactly. Row-sum l via MFMA ones-trick.
// Halves merged at the end via LDS (pure o/l add).
__global__ __launch_bounds__(512) void attn_mfma_kernel(
    const short* __restrict__ qg, const short* __restrict__ kg,
    const short* __restrict__ vtg, const int* __restrict__ mask,
    const int* __restrict__ mflags, unsigned short* __restrict__ attn_out)
{
    __shared__ alignas(16) short lk[2][2][2048];   // [buf][half][64x32]
    __shared__ alignas(16) short lv[2][2][2048];   // [buf][half][32x64]

    const int tid  = threadIdx.x;
    const int lane = tid & 63;
    const int wid  = tid >> 6;       // 0..7
    const int c    = lane & 15;
    const int g    = lane >> 4;
    const int half = wid >> 2;       // compute key-half
    const int qs   = wid & 3;        // q-group
    // XCD swizzle: 512 blocks, 8 XCDs
    const int p    = ((int)blockIdx.x & 7)*64 + ((int)blockIdx.x >> 3);
    const int bh   = p >> 4;
    const int qt   = p & 15;
    const int b    = bh >> 3;
    const int h    = bh & 7;
    const int q0   = qt*128 + qs*32;

    const short* qrow = qg + ((size_t)bh*S_ + q0 + c)*D_ + g*8;
    const short8 qfA = *(const short8*)(qrow);
    const short8 qfB = *(const short8*)(qrow + 16*D_);
    const short* kbase = kg  + (size_t)bh*S_*D_;
    const short* vbase = vtg + (size_t)bh*D_*S_;
    const int*   mrow  = mask + b*S_;

    const int fl = (lane < 32) ? mflags[b*32 + lane] : 0;
    const unsigned long long mbits = __ballot(fl != 0);

    // staging roles: wid 0,1 -> K half0; 2,3 -> K half1; 4,5 -> V half0; 6,7 -> V half1
    const int sthalf = (wid >> 1) & 1;
    const int subw   = wid & 1;
    const short* sbase; int soff0, soff1, sinc, dchunk;
    if (wid < 4) {
        const int R0 = subw*32 + (lane >> 2);
        const int R1 = R0 + 16;
        const int s  = lane & 3;
        soff0 = R0*D_ + ((s ^ ((R0 >> 1) & 3)) << 3);
        soff1 = R1*D_ + ((s ^ ((R1 >> 1) & 3)) << 3);
        sbase = kbase + (size_t)sthalf*16*64*D_;
        sinc  = 64*D_;
        dchunk = subw*1024;
    } else {
        const int r0 = subw*16 + (lane >> 3);
        const int r1 = r0 + 8;
        const int s  = lane & 7;
        soff0 = r0*S_ + ((s ^ (r0 & 7)) << 3);
        soff1 = r1*S_ + ((s ^ (r1 & 7)) << 3);
        sbase = vbase + sthalf*16*64;
        sinc  = 64;
        dchunk = subw*1024;
    }

    const int kaddr = c*D_ + ((g ^ ((c >> 1) & 3)) << 3);
    const int va0   = c*64 + ((g       ^ (c & 7)) << 3);
    const int va1   = c*64 + (((g + 4) ^ (c & 7)) << 3);
    const f32x4 zero = {0.f,0.f,0.f,0.f};
    const short8 ones = { (short)0x3F80, (short)0x3F80, (short)0x3F80, (short)0x3F80,
                          (short)0x3F80, (short)0x3F80, (short)0x3F80, (short)0x3F80 };
    f32x4 oA0 = zero, oA1 = zero, oB0 = zero, oB1 = zero;
    f32x4 lAacc = zero, lBacc = zero;

    {   // prologue: stage tile 0 of both halves into buf 0
        short* d0 = (wid < 4 ? &lk[0][sthalf][0] : &lv[0][sthalf][0]) + dchunk;
        gld16(sbase + soff0, d0);
        gld16(sbase + soff1, d0 + 512);
    }
    __syncthreads();

    int buf = 0;
    for (int t = 0; t < 16; ++t) {
        if (t < 15) {
            const short* sp = sbase + (size_t)(t + 1)*sinc;
            short* d0 = (wid < 4 ? &lk[buf ^ 1][sthalf][0] : &lv[buf ^ 1][sthalf][0]) + dchunk;
            gld16(sp + soff0, d0);
            gld16(sp + soff1, d0 + 512);
        }
        const short* LK = &lk[buf][half][0];
        const short* LV = &lv[buf][half][0];
        const short8 kf0 = *(const short8*)(LK + kaddr);
        const short8 kf1 = *(const short8*)(LK + kaddr + 512);
        const short8 kf2 = *(const short8*)(LK + kaddr + 1024);
        const short8 kf3 = *(const short8*)(LK + kaddr + 1536);
        __builtin_amdgcn_s_setprio(1);
        f32x4 sA0 = __builtin_amdgcn_mfma_f32_16x16x32_bf16(kf0, qfA, zero, 0, 0, 0);
        f32x4 sA1 = __builtin_amdgcn_mfma_f32_16x16x32_bf16(kf1, qfA, zero, 0, 0, 0);
        f32x4 sA2 = __builtin_amdgcn_mfma_f32_16x16x32_bf16(kf2, qfA, zero, 0, 0, 0);
        f32x4 sA3 = __builtin_amdgcn_mfma_f32_16x16x32_bf16(kf3, qfA, zero, 0, 0, 0);
        f32x4 sB0 = __builtin_amdgcn_mfma_f32_16x16x32_bf16(kf0, qfB, zero, 0, 0, 0);
        f32x4 sB1 = __builtin_amdgcn_mfma_f32_16x16x32_bf16(kf1, qfB, zero, 0, 0, 0);
        f32x4 sB2 = __builtin_amdgcn_mfma_f32_16x16x32_bf16(kf2, qfB, zero, 0, 0, 0);
        f32x4 sB3 = __builtin_amdgcn_mfma_f32_16x16x32_bf16(kf3, qfB, zero, 0, 0, 0);
        __builtin_amdgcn_s_setprio(0);
        // mask; key = 64*tt + 32*(f>>1) + 8g + 4*(f&1) + r
        const int tt = half*16 + t;
        if ((mbits >> tt) & 1ull) {
            const int kb = tt*64 + 8*g;
            #pragma unroll
            for (int r = 0; r < 4; ++r) {
                if (mrow[kb      + r] == 0) { sA0[r] = -1e20f; sB0[r] = -1e20f; }
                if (mrow[kb + 4  + r] == 0) { sA1[r] = -1e20f; sB1[r] = -1e20f; }
                if (mrow[kb + 32 + r] == 0) { sA2[r] = -1e20f; sB2[r] = -1e20f; }
                if (mrow[kb + 36 + r] == 0) { sA3[r] = -1e20f; sB3[r] = -1e20f; }
            }
        }
        f32x4 pA0, pA1, pA2, pA3, pB0, pB1, pB2, pB3;
        #pragma unroll
        for (int r = 0; r < 4; ++r) {
            pA0[r] = fexp2(sA0[r]); pA1[r] = fexp2(sA1[r]);
            pA2[r] = fexp2(sA2[r]); pA3[r] = fexp2(sA3[r]);
            pB0[r] = fexp2(sB0[r]); pB1[r] = fexp2(sB1[r]);
            pB2[r] = fexp2(sB2[r]); pB3[r] = fexp2(sB3[r]);
        }
        const short8 pafA0 = __builtin_bit_cast(short8,
            (u32x4){ cvtpk_bf16(pA0[0],pA0[1]), cvtpk_bf16(pA0[2],pA0[3]),
                     cvtpk_bf16(pA1[0],pA1[1]), cvtpk_bf16(pA1[2],pA1[3]) });
        const short8 pafA1 = __builtin_bit_cast(short8,
            (u32x4){ cvtpk_bf16(pA2[0],pA2[1]), cvtpk_bf16(pA2[2],pA2[3]),
                     cvtpk_bf16(pA3[0],pA3[1]), cvtpk_bf16(pA3[2],pA3[3]) });
        const short8 pafB0 = __builtin_bit_cast(short8,
            (u32x4){ cvtpk_bf16(pB0[0],pB0[1]), cvtpk_bf16(pB0[2],pB0[3]),
                     cvtpk_bf16(pB1[0],pB1[1]), cvtpk_bf16(pB1[2],pB1[3]) });
        const short8 pafB1 = __builtin_bit_cast(short8,
            (u32x4){ cvtpk_bf16(pB2[0],pB2[1]), cvtpk_bf16(pB2[2],pB2[3]),
                     cvtpk_bf16(pB3[0],pB3[1]), cvtpk_bf16(pB3[2],pB3[3]) });
        const short8 vf0 = *(const short8*)(LV + va0);
        const short8 vf1 = *(const short8*)(LV + va1);
        const short8 vf2 = *(const short8*)(LV + va0 + 1024);
        const short8 vf3 = *(const short8*)(LV + va1 + 1024);
        __builtin_amdgcn_s_setprio(1);
        oA0 = __builtin_amdgcn_mfma_f32_16x16x32_bf16(vf0, pafA0, oA0, 0, 0, 0);
        oA0 = __builtin_amdgcn_mfma_f32_16x16x32_bf16(vf1, pafA1, oA0, 0, 0, 0);
        oA1 = __builtin_amdgcn_mfma_f32_16x16x32_bf16(vf2, pafA0, oA1, 0, 0, 0);
        oA1 = __builtin_amdgcn_mfma_f32_16x16x32_bf16(vf3, pafA1, oA1, 0, 0, 0);
        oB0 = __builtin_amdgcn_mfma_f32_16x16x32_bf16(vf0, pafB0, oB0, 0, 0, 0);
        oB0 = __builtin_amdgcn_mfma_f32_16x16x32_bf16(vf1, pafB1, oB0, 0, 0, 0);
        oB1 = __builtin_amdgcn_mfma_f32_16x16x32_bf16(vf2, pafB0, oB1, 0, 0, 0);
        oB1 = __builtin_amdgcn_mfma_f32_16x16x32_bf16(vf3, pafB1, oB1, 0, 0, 0);
        lAacc = __builtin_amdgcn_mfma_f32_16x16x32_bf16(ones, pafA0, lAacc, 0, 0, 0);
        lAacc = __builtin_amdgcn_mfma_f32_16x16x32_bf16(ones, pafA1, lAacc, 0, 0, 0);
        lBacc = __builtin_amdgcn_mfma_f32_16x16x32_bf16(ones, pafB0, lBacc, 0, 0, 0);
        lBacc = __builtin_amdgcn_mfma_f32_16x16x32_bf16(ones, pafB1, lBacc, 0, 0, 0);
        __builtin_amdgcn_s_setprio(0);
        __syncthreads();
        buf ^= 1;
    }
    // ---- merge the two key halves (pure o/l add; reuse staging LDS) ----
    float* oM = (float*)&lk[0][0][0];   // [4 qs][64 lane][16] f32 = 16KB
    float* lM = (float*)&lv[0][0][0];   // [4 qs][64 lane][2]  f32 = 2KB
    if (half == 1) {
        float* o = oM + (qs*64 + lane)*16;
        #pragma unroll
        for (int r = 0; r < 4; ++r) {
            o[r]      = oA0[r];
            o[4 + r]  = oA1[r];
            o[8 + r]  = oB0[r];
            o[12 + r] = oB1[r];
        }
        lM[(qs*64 + lane)*2 + 0] = lAacc[0];
        lM[(qs*64 + lane)*2 + 1] = lBacc[0];
    }
    __syncthreads();
    if (half == 0) {
        const float* o = oM + (qs*64 + lane)*16;
        const float lA = lAacc[0] + lM[(qs*64 + lane)*2 + 0];
        const float lB = lBacc[0] + lM[(qs*64 + lane)*2 + 1];
        const float invA = 1.0f / lA, invB = 1.0f / lB;
        unsigned short* orowA = attn_out + ((size_t)b*S_ + q0 + c)*E_ + h*D_ + g*4;
        unsigned short* orowB = orowA + (size_t)16*E_;
        uint2 a0, a1, b0, b1;
        a0.x = cvtpk_bf16((oA0[0]+o[0])*invA,  (oA0[1]+o[1])*invA);
        a0.y = cvtpk_bf16((oA0[2]+o[2])*invA,  (oA0[3]+o[3])*invA);
        a1.x = cvtpk_bf16((oA1[0]+o[4])*invA,  (oA1[1]+o[5])*invA);
        a1.y = cvtpk_bf16((oA1[2]+o[6])*invA,  (oA1[3]+o[7])*invA);
        b0.x = cvtpk_bf16((oB0[0]+o[8])*invB,  (oB0[1]+o[9])*invB);
        b0.y = cvtpk_bf16((oB0[2]+o[10])*invB, (oB0[3]+o[11])*invB);
        b1.x = cvtpk_bf16((oB1[0]+o[12])*invB, (oB1[1]+o[13])*invB);
        b1.y = cvtpk_bf16((oB1[2]+o[14])*invB, (oB1[3]+o[15])*invB);
        *(uint2*)(orowA)      = a0;
        *(uint2*)(orowA + 16) = a1;
        *(uint2*)(orowB)      = b0;
        *(uint2*)(orowB + 16) = b1;
    }
}

// ---------------- fused GEMM + series decomposition ----------------
// C = A[M,K] @ WT[256,K]^T + bias + R  (full E=256 row per block, BM=32),
// then res = C - movavg25(C) over the E axis; writes o32 (fp32) and/or ob (bf16).
// Double-buffered staging (R12 config). RBF16: residual read as bf16.
template<int WF32, int WBF16, int RBF16>
__global__ __launch_bounds__(256) void mgemm_dec_kernel(
    const short* __restrict__ A, const short* __restrict__ WT,
    const float* __restrict__ bias, const void* __restrict__ Rres,
    float* __restrict__ o32, unsigned short* __restrict__ ob,
    int M, int K)
{
    __shared__ alignas(16) short stage[2][18432];   // per buf: As 2048 sh + Bs 16384 sh
    float* dec = (float*)&stage[0][0];              // [32][261] fp32 = 33408 B
    const int t = threadIdx.x, w = t >> 6, lane = t & 63;
    const int col = lane & 15, grp = lane >> 4;
    const int wm = w >> 1, wn = w & 1;
    const int nwg = gridDim.x;
    const int bm = ((int)blockIdx.x & 7)*(nwg >> 3) + ((int)blockIdx.x >> 3);
    const int arow = t >> 3, ac = t & 7;

    f32x4 acc[8];
    #pragma unroll
    for (int j = 0; j < 8; ++j) acc[j] = (f32x4){0.f,0.f,0.f,0.f};

    {
        const int row = arow;
        gld16(A + (size_t)(bm*32 + row)*K + ((ac ^ (row & 7)) << 3),
              &stage[0][0] + w*512);
        #pragma unroll
        for (int b2 = 0; b2 < 8; ++b2) {
            const int rowb = b2*32 + arow;
            gld16(WT + (size_t)rowb*K + ((ac ^ (rowb & 7)) << 3),
                  &stage[0][2048] + b2*2048 + w*512);
        }
    }
    __syncthreads();

    int buf = 0;
    for (int kb = 0; kb < K; kb += 64) {
        if (kb + 64 < K) {
            const int row = arow;
            gld16(A + (size_t)(bm*32 + row)*K + kb + 64 + ((ac ^ (row & 7)) << 3),
                  &stage[buf ^ 1][0] + w*512);
            #pragma unroll
            for (int b2 = 0; b2 < 8; ++b2) {
                const int rowb = b2*32 + arow;
                gld16(WT + (size_t)rowb*K + kb + 64 + ((ac ^ (rowb & 7)) << 3),
                      &stage[buf ^ 1][2048] + b2*2048 + w*512);
            }
        }
        const short* As_ = &stage[buf][0];
        const short* Bs_ = &stage[buf][2048];
        #pragma unroll
        for (int s = 0; s < 2; ++s) {
            const short8 af = lds_frag(As_, wm*16 + col, s*4 + grp);
            #pragma unroll
            for (int fc = 0; fc < 8; ++fc) {
                const short8 bf_ = lds_frag(Bs_, wn*128 + fc*16 + col, s*4 + grp);
                acc[fc] = __builtin_amdgcn_mfma_f32_16x16x32_bf16(af, bf_, acc[fc], 0, 0, 0);
            }
        }
        __syncthreads();
        buf ^= 1;
    }

    // epilogue: bias + residual -> LDS dec[32][261]
    #pragma unroll
    for (int fc = 0; fc < 8; ++fc) {
        const int n = wn*128 + fc*16 + col;
        const float bs = bias[n];
        #pragma unroll
        for (int reg = 0; reg < 4; ++reg) {
            const int m = wm*16 + grp*4 + reg;
            float v = acc[fc][reg] + bs;
            if (RBF16) v += bf16_to_f32(((const unsigned short*)Rres)[(size_t)(bm*32 + m)*E_ + n]);
            else       v += ((const float*)Rres)[(size_t)(bm*32 + m)*E_ + n];
            dec[m*261 + n] = v;
        }
    }
    __syncthreads();
    const int row = t & 31, ch = t >> 5;
    const int c0 = ch * 32;
    const float* dr = dec + row*261;
    float sum = 0.f;
    #pragma unroll
    for (int j = -12; j <= 12; ++j) {
        int jj = c0 + j;
        jj = jj < 0 ? 0 : (jj > 255 ? 255 : jj);
        sum += dr[jj];
    }
    float res[32];
    #pragma unroll
    for (int i = 0; i < 32; ++i) {
        const int cc = c0 + i;
        res[i] = dr[cc] - sum * (1.0f/25.0f);
        const int hi = cc + 13 > 255 ? 255 : cc + 13;
        const int lo = cc - 12 < 0 ? 0 : cc - 12;
        sum += dr[hi] - dr[lo];
    }
    const size_t gro = (size_t)(bm*32 + row)*E_ + c0;
    if (WF32) {
        #pragma unroll
        for (int i = 0; i < 8; ++i)
            *(f32x4*)(o32 + gro + i*4) = (f32x4){res[4*i], res[4*i+1], res[4*i+2], res[4*i+3]};
    }
    if (WBF16) {
        #pragma unroll
        for (int i = 0; i < 4; ++i) {
            u32x4 pk;
            #pragma unroll
            for (int j = 0; j < 4; ++j)
                pk[j] = cvtpk_bf16(res[8*i + 2*j], res[8*i + 2*j + 1]);
            *(u32x4*)(ob + gro + i*8) = pk;
        }
    }
}

// ---------------- bf16 MFMA GEMM: C[M,N] = op(A[M,K] @ WT[N,K]^T + bias) ----------------
// BK=64, 4 waves. DB=1: double-buffered (64^2 only). XCD-chunk swizzle.
template<int BM, int BN, int DB, int RELU, int RESID, int WF32, int WBF16>
__global__ __launch_bounds__(256) void mgemm_kernel(
    const short* __restrict__ A, const short* __restrict__ WT,
    const float* __restrict__ bias, const float* __restrict__ R,
    float* __restrict__ C32, unsigned short* __restrict__ Cb,
    int M, int N, int K)
{
    constexpr int FR = BM / 32;
    constexpr int FC = BN / 32;
    constexpr int NB = DB ? 2 : 1;
    __shared__ alignas(16) short As[NB][BM*64];
    __shared__ alignas(16) short Bs[NB][BN*64];
    const int t = threadIdx.x, w = t >> 6, lane = t & 63;
    const int col = lane & 15, grp = lane >> 4;
    const int wm = w >> 1, wn = w & 1;
    const int gx = N / BN;
    const int nwg = gridDim.x;
    const int lin = ((int)blockIdx.x & 7)*(nwg >> 3) + ((int)blockIdx.x >> 3);
    const int bm = lin / gx, bn = lin % gx;
    const int arow = t >> 3, ac = t & 7;

    f32x4 acc[FR][FC];
    #pragma unroll
    for (int i = 0; i < FR; ++i)
        #pragma unroll
        for (int j = 0; j < FC; ++j) acc[i][j] = (f32x4){0.f,0.f,0.f,0.f};

    if (DB) {
        #pragma unroll
        for (int b2 = 0; b2 < BM/32; ++b2) {
            const int row = b2*32 + arow;
            gld16(A + (size_t)(bm*BM + row)*K + ((ac ^ (row & 7)) << 3),
                  &As[0][0] + b2*2048 + w*512);
        }
        #pragma unroll
        for (int b2 = 0; b2 < BN/32; ++b2) {
            const int row = b2*32 + arow;
            gld16(WT + (size_t)(bn*BN + row)*K + ((ac ^ (row & 7)) << 3),
                  &Bs[0][0] + b2*2048 + w*512);
        }
        __syncthreads();
        int buf = 0;
        for (int kb = 0; kb < K; kb += 64) {
            if (kb + 64 < K) {
                #pragma unroll
                for (int b2 = 0; b2 < BM/32; ++b2) {
                    const int row = b2*32 + arow;
                    gld16(A + (size_t)(bm*BM + row)*K + kb + 64 + ((ac ^ (row & 7)) << 3),
                          &As[buf ^ 1][0] + b2*2048 + w*512);
                }
                #pragma unroll
                for (int b2 = 0; b2 < BN/32; ++b2) {
                    const int row = b2*32 + arow;
                    gld16(WT + (size_t)(bn*BN + row)*K + kb + 64 + ((ac ^ (row & 7)) << 3),
                          &Bs[buf ^ 1][0] + b2*2048 + w*512);
                }
            }
            #pragma unroll
            for (int s = 0; s < 2; ++s) {
                short8 af[FR], bf_[FC];
                #pragma unroll
                for (int fr = 0; fr < FR; ++fr)
                    af[fr] = lds_frag(&As[buf][0], wm*(BM/2) + fr*16 + col, s*4 + grp);
                #pragma unroll
                for (int fc = 0; fc < FC; ++fc)
                    bf_[fc] = lds_frag(&Bs[buf][0], wn*(BN/2) + fc*16 + col, s*4 + grp);
                #pragma unroll
                for (int fr = 0; fr < FR; ++fr)
                    #pragma unroll
                    for (int fc = 0; fc < FC; ++fc)
                        acc[fr][fc] = __builtin_amdgcn_mfma_f32_16x16x32_bf16(af[fr], bf_[fc], acc[fr][fc], 0, 0, 0);
            }
            __syncthreads();
            buf ^= 1;
        }
    } else {
        for (int kb = 0; kb < K; kb += 64) {
            #pragma unroll
            for (int b2 = 0; b2 < BM/32; ++b2) {
                const int row = b2*32 + arow;
                gld16(A + (size_t)(bm*BM + row)*K + kb + ((ac ^ (row & 7)) << 3),
                      &As[0][0] + b2*2048 + w*512);
            }
            #pragma unroll
            for (int b2 = 0; b2 < BN/32; ++b2) {
                const int row = b2*32 + arow;
                gld16(WT + (size_t)(bn*BN + row)*K + kb + ((ac ^ (row & 7)) << 3),
                      &Bs[0][0] + b2*2048 + w*512);
            }
            __syncthreads();
            #pragma unroll
            for (int s = 0; s < 2; ++s) {
                short8 af[FR], bf_[FC];
                #pragma unroll
                for (int fr = 0; fr < FR; ++fr)
                    af[fr] = lds_frag(&As[0][0], wm*(BM/2) + fr*16 + col, s*4 + grp);
                #pragma unroll
                for (int fc = 0; fc < FC; ++fc)
                    bf_[fc] = lds_frag(&Bs[0][0], wn*(BN/2) + fc*16 + col, s*4 + grp);
                #pragma unroll
                for (int fr = 0; fr < FR; ++fr)
                    #pragma unroll
                    for (int fc = 0; fc < FC; ++fc)
                        acc[fr][fc] = __builtin_amdgcn_mfma_f32_16x16x32_bf16(af[fr], bf_[fc], acc[fr][fc], 0, 0, 0);
            }
            __syncthreads();
        }
    }

    #pragma unroll
    for (int fc = 0; fc < FC; ++fc) {
        const int n = bn*BN + wn*(BN/2) + fc*16 + col;
        const float bs = bias[n];
        #pragma unroll
        for (int fr = 0; fr < FR; ++fr) {
            #pragma unroll
            for (int reg = 0; reg < 4; ++reg) {
                const int m = bm*BM + wm*(BM/2) + fr*16 + grp*4 + reg;
                float v = acc[fr][fc][reg] + bs;
                if (RELU) v = fmaxf(v, 0.f);
                if (RESID) v += R[(size_t)m*N + n];
                if (WF32) C32[(size_t)m*N + n] = v;
                if (WBF16) Cb[(size_t)m*N + n] = round_bf16(v);
            }
        }
    }
}

extern "C" void kernel_launch(void* const* d_in, const int* in_sizes, int n_in,
                              void* d_out, int out_size, void* d_ws, size_t ws_size,
                              hipStream_t stream) {
    const float* x     = (const float*)d_in[0];
    const int*   mask  = (const int*)  d_in[1];
    const float* wq    = (const float*)d_in[2];
    const float* wk    = (const float*)d_in[3];
    const float* wv    = (const float*)d_in[4];
    const float* w_out = (const float*)d_in[5];
    const float* b_out = (const float*)d_in[6];
    const float* ff_w1 = (const float*)d_in[7];
    const float* ff_b1 = (const float*)d_in[8];
    const float* ff_w2 = (const float*)d_in[9];
    const float* ff_b2 = (const float*)d_in[10];
    const float* pr_w1 = (const float*)d_in[11];
    const float* pr_b1 = (const float*)d_in[12];
    const float* pr_w2 = (const float*)d_in[13];
    const float* pr_b2 = (const float*)d_in[14];
    float* out = (float*)d_out;

    char* ws = (char*)d_ws;
    const size_t MB = 1024ull*1024ull;
    const size_t KB = 1024ull;
    bf16*  qb    = (bf16*)(ws + 0*MB);                       // 4MB
    bf16*  kbf   = (bf16*)(ws + 4*MB);                       // 4MB
    bf16*  vtb   = (bf16*)(ws + 12*MB);                      // 4MB
    unsigned short* attnb = (unsigned short*)(ws + 16*MB);   // 4MB
    unsigned short* yb  = (unsigned short*)(ws + 36*MB);     // 4MB
    unsigned short* h1  = (unsigned short*)(ws + 0*MB);      // 16MB (qkv dead)
    unsigned short* s2b = (unsigned short*)(ws + 16*MB);     // 4MB (attnb dead)
    unsigned short* h2  = (unsigned short*)(ws + 0*MB);      // 16MB (h1 dead)
    unsigned short* woT = (unsigned short*)(ws + 40*MB);                // 128KB
    unsigned short* f1T = (unsigned short*)(ws + 40*MB + 128*KB);       // 512KB
    unsigned short* f2T = (unsigned short*)(ws + 40*MB + 640*KB);       // 512KB
    unsigned short* p1T = (unsigned short*)(ws + 40*MB + 1152*KB);      // 512KB
    unsigned short* p2T = (unsigned short*)(ws + 40*MB + 1664*KB);      // 512KB
    int*            mfl = (int*)           (ws + 40*MB + 2176*KB);      // 512B

    // 1. fused QKV (+V-transpose) + weight prep + maskscan
    qkv_prep_kernel<<<1601, 256, 0, stream>>>(x, wq, wk, wv, qb, kbf,
                                              (unsigned short*)vtb,
                                              w_out, ff_w1, ff_w2, pr_w1, pr_w2,
                                              woT, f1T, f2T, p1T, p2T, mask, mfl);
    // 2. MFMA flash attention (8 waves: 4 q-groups x 2 key-halves) -> bf16
    attn_mfma_kernel<<<B_*H_*S_/128, 512, 0, stream>>>(
        (const short*)qb, (const short*)kbf, (const short*)vtb, mask, mfl, attnb);
    // 3. fused: x1 = x + attn@w_out + b_out ; y = decomp(x1)  -> yb (bf16 only)
    mgemm_dec_kernel<0,1,0><<<NTOK/32, 256, 0, stream>>>(
        (const short*)attnb, (const short*)woT, b_out, x, nullptr, yb, NTOK, E_);
    // 4. FFN: h1 = relu(y @ ff_w1 + b1)   (128x128, single-buffered)
    mgemm_kernel<128,128,0,1,0,0,1><<<(NTOK/128)*(FF_/128), 256, 0, stream>>>(
        (const short*)yb, (const short*)f1T, ff_b1, nullptr, nullptr, h1, NTOK, FF_, E_);
    // 5. fused: s = y + h1@ff_w2 + b2 ; s2 = decomp(s)  -> s2b  (residual = yb, bf16)
    mgemm_dec_kernel<0,1,1><<<NTOK/32, 256, 0, stream>>>(
        (const short*)h1, (const short*)f2T, ff_b2, yb, nullptr, s2b, NTOK, FF_);
    // 6. projection FFN  (128x128, single-buffered)
    mgemm_kernel<128,128,0,1,0,0,1><<<(NTOK/128)*(FF_/128), 256, 0, stream>>>(
        (const short*)s2b, (const short*)p1T, pr_b1, nullptr, nullptr, h2, NTOK, FF_, E_);
    mgemm_kernel<64,64,1,0,0,1,0><<<(NTOK/64)*(E_/64), 256, 0, stream>>>(
        (const short*)h2, (const short*)p2T, pr_b2, nullptr, out, nullptr, NTOK, E_, FF_);
}